// Round 2
// baseline (118.509 us; speedup 1.0000x reference)
//
#include <hip/hip_runtime.h>
#include <math.h>

#define CLASS_P 360
#define ROW_STRIDE 4320      // C * P = 12 * 360
#define NF4 90               // float4 chunks per window (360/4)

__device__ __forceinline__ float wave_sum(float v) {
    #pragma unroll
    for (int o = 32; o > 0; o >>= 1) v += __shfl_xor(v, o);
    return v;
}
__device__ __forceinline__ float wave_max(float v) {
    #pragma unroll
    for (int o = 32; o > 0; o >>= 1) v = fmaxf(v, __shfl_xor(v, o));
    return v;
}

// One 64-lane wave per row, 4 rows per 256-thread block, fused grid reduction
// via the deterministic last-block pattern (int atomic counter, fixed-order
// final sum -> bit-stable across graph replays).
__global__ __launch_bounds__(256) void vp_loss_fused(
        const float* __restrict__ preds,
        const float* __restrict__ labels,
        const int*   __restrict__ cls,
        float* __restrict__ out,
        unsigned int* __restrict__ counter,
        float* __restrict__ partial,
        int B, int nblk) {
    const int wid  = threadIdx.x >> 6;
    const int lane = threadIdx.x & 63;
    const int row  = blockIdx.x * 4 + wid;

    __shared__ float sm[4];
    __shared__ int isLast;

    float acc = 0.f;
    if (row < B) {
        const size_t base = (size_t)row * ROW_STRIDE + (size_t)cls[row] * CLASS_P;
        const float4* __restrict__ p4 = (const float4*)(preds + base);
        const float4* __restrict__ l4 = (const float4*)(labels + base);

        // Lane i holds float4 i (i<64) and float4 i+64 (i<26): 90 float4 total.
        float4 a0 = p4[lane];
        float4 b0 = l4[lane];
        const bool has2 = lane < (NF4 - 64);   // lane < 26
        float4 a1 = make_float4(0.f, 0.f, 0.f, 0.f);
        float4 b1 = a1;
        if (has2) { a1 = p4[lane + 64]; b1 = l4[lane + 64]; }

        // Phase 1: L1 norm and max of the window.
        float sabs = fabsf(a0.x) + fabsf(a0.y) + fabsf(a0.z) + fabsf(a0.w);
        float pmax = fmaxf(fmaxf(a0.x, a0.y), fmaxf(a0.z, a0.w));
        if (has2) {
            sabs += fabsf(a1.x) + fabsf(a1.y) + fabsf(a1.z) + fabsf(a1.w);
            pmax  = fmaxf(pmax, fmaxf(fmaxf(a1.x, a1.y), fmaxf(a1.z, a1.w)));
        }
        sabs = wave_sum(sabs);
        pmax = wave_max(pmax);

        const float inv = 1.0f / sabs;     // scaled_j = pw_j * inv
        const float m   = pmax * inv;      // max(scaled) (inv > 0, monotone)

        // Phase 2: sum exp(scaled - m)
        float se = __expf(a0.x * inv - m) + __expf(a0.y * inv - m)
                 + __expf(a0.z * inv - m) + __expf(a0.w * inv - m);
        if (has2)
            se += __expf(a1.x * inv - m) + __expf(a1.y * inv - m)
                + __expf(a1.z * inv - m) + __expf(a1.w * inv - m);
        se = wave_sum(se);
        const float lse = __logf(se) + m;  // logsumexp(scaled)

        // Phase 3: sum lw * (lse - scaled)   ( == -sum lw * log_softmax )
        acc = b0.x * (lse - a0.x * inv) + b0.y * (lse - a0.y * inv)
            + b0.z * (lse - a0.z * inv) + b0.w * (lse - a0.w * inv);
        if (has2)
            acc += b1.x * (lse - a1.x * inv) + b1.y * (lse - a1.y * inv)
                 + b1.z * (lse - a1.z * inv) + b1.w * (lse - a1.w * inv);
        acc = wave_sum(acc);
    }

    // Block partial: 4 wave leaders -> LDS -> thread 0.
    if (lane == 0) sm[wid] = acc;
    __syncthreads();
    if (threadIdx.x == 0) {
        partial[blockIdx.x] = sm[0] + sm[1] + sm[2] + sm[3];
        __threadfence();                       // release partial before counter
        unsigned int old = atomicAdd(counter, 1u);
        isLast = (old == (unsigned int)(nblk - 1)) ? 1 : 0;
    }
    __syncthreads();

    if (isLast) {
        __threadfence();                       // acquire all partials
        float v = 0.f;
        for (int i = threadIdx.x; i < nblk; i += 256) v += partial[i];
        v = wave_sum(v);
        if (lane == 0) sm[wid] = v;
        __syncthreads();
        if (threadIdx.x == 0) out[0] = sm[0] + sm[1] + sm[2] + sm[3];
    }
}

extern "C" void kernel_launch(void* const* d_in, const int* in_sizes, int n_in,
                              void* d_out, int out_size, void* d_ws, size_t ws_size,
                              hipStream_t stream) {
    const float* preds  = (const float*)d_in[0];
    const float* labels = (const float*)d_in[1];
    const int*   cls    = (const int*)d_in[2];
    float* out = (float*)d_out;

    unsigned int* counter = (unsigned int*)d_ws;                 // 4 B @ offset 0
    float* partial = (float*)((char*)d_ws + 256);                // aligned partials

    const int B = in_sizes[2];               // 16384 rows
    const int blocks = (B + 3) / 4;          // 4 rows (waves) per block

    hipMemsetAsync(counter, 0, sizeof(unsigned int), stream);    // capturable
    vp_loss_fused<<<blocks, 256, 0, stream>>>(preds, labels, cls, out,
                                              counter, partial, B, blocks);
}

// Round 3
// 19.659 us; speedup vs baseline: 6.0284x; 6.0284x over previous
//
#include <hip/hip_runtime.h>
#include <math.h>

#define CLASS_P 360
#define ROW_STRIDE 4320      // C * P = 12 * 360
#define NF4 90               // float4 chunks per window (360/4)
#define RPW 4                // rows per wave

__device__ __forceinline__ float wave_sum(float v) {
    #pragma unroll
    for (int o = 32; o > 0; o >>= 1) v += __shfl_xor(v, o);
    return v;
}
__device__ __forceinline__ float wave_max(float v) {
    #pragma unroll
    for (int o = 32; o > 0; o >>= 1) v = fmaxf(v, __shfl_xor(v, o));
    return v;
}

// 4 waves/block, RPW rows per wave, all loads issued up front (ILP),
// phase-3 accumulated per-lane across rows -> single wave_sum at end.
__global__ __launch_bounds__(256) void vp_rows(
        const float* __restrict__ preds,
        const float* __restrict__ labels,
        const int*   __restrict__ cls,
        float* __restrict__ partial,
        int B) {
    const int wid  = threadIdx.x >> 6;
    const int lane = threadIdx.x & 63;
    const int wave = blockIdx.x * 4 + wid;
    const int r0   = wave * RPW;
    const bool has2 = lane < (NF4 - 64);   // lane < 26

    float4 a0[RPW], b0[RPW], a1[RPW], b1[RPW];
    float  wgt[RPW];

    #pragma unroll
    for (int k = 0; k < RPW; k++) {
        const int r  = r0 + k;
        const int rr = (r < B) ? r : 0;
        wgt[k] = (r < B) ? 1.0f : 0.0f;
        const size_t base = (size_t)rr * ROW_STRIDE + (size_t)cls[rr] * CLASS_P;
        const float4* __restrict__ p4 = (const float4*)(preds + base);
        const float4* __restrict__ l4 = (const float4*)(labels + base);
        a0[k] = p4[lane];
        b0[k] = l4[lane];
        a1[k] = make_float4(0.f, 0.f, 0.f, 0.f);
        b1[k] = a1[k];
        if (has2) { a1[k] = p4[lane + 64]; b1[k] = l4[lane + 64]; }
    }

    float acc = 0.f;
    #pragma unroll
    for (int k = 0; k < RPW; k++) {
        // Phase 1: L1 norm + max (two independent shuffle chains).
        float sabs = fabsf(a0[k].x) + fabsf(a0[k].y) + fabsf(a0[k].z) + fabsf(a0[k].w)
                   + fabsf(a1[k].x) + fabsf(a1[k].y) + fabsf(a1[k].z) + fabsf(a1[k].w);
        float pmax = fmaxf(fmaxf(a0[k].x, a0[k].y), fmaxf(a0[k].z, a0[k].w));
        if (has2)
            pmax = fmaxf(pmax, fmaxf(fmaxf(a1[k].x, a1[k].y), fmaxf(a1[k].z, a1[k].w)));
        sabs = wave_sum(sabs);
        pmax = wave_max(pmax);

        const float inv = 1.0f / sabs;
        const float m   = pmax * inv;

        // Phase 2: sum exp(scaled - m)
        float se = __expf(a0[k].x * inv - m) + __expf(a0[k].y * inv - m)
                 + __expf(a0[k].z * inv - m) + __expf(a0[k].w * inv - m);
        if (has2)
            se += __expf(a1[k].x * inv - m) + __expf(a1[k].y * inv - m)
                + __expf(a1[k].z * inv - m) + __expf(a1[k].w * inv - m);
        se = wave_sum(se);
        const float lse = __logf(se) + m;

        // Phase 3: per-lane accumulation only (one wave_sum after the loop).
        float t = b0[k].x * (lse - a0[k].x * inv) + b0[k].y * (lse - a0[k].y * inv)
                + b0[k].z * (lse - a0[k].z * inv) + b0[k].w * (lse - a0[k].w * inv);
        if (has2)
            t += b1[k].x * (lse - a1[k].x * inv) + b1[k].y * (lse - a1[k].y * inv)
               + b1[k].z * (lse - a1[k].z * inv) + b1[k].w * (lse - a1[k].w * inv);
        acc += wgt[k] * t;
    }
    acc = wave_sum(acc);

    __shared__ float sm[4];
    if (lane == 0) sm[wid] = acc;
    __syncthreads();
    if (threadIdx.x == 0) partial[blockIdx.x] = sm[0] + sm[1] + sm[2] + sm[3];
}

// Single-block deterministic reduction of n partials -> out[0].
__global__ __launch_bounds__(256) void vp_reduce(
        const float* __restrict__ partial, float* __restrict__ out, int n) {
    __shared__ float sm[4];
    float acc = 0.f;
    for (int i = threadIdx.x; i < n; i += 256) acc += partial[i];
    acc = wave_sum(acc);
    const int wid = threadIdx.x >> 6, lane = threadIdx.x & 63;
    if (lane == 0) sm[wid] = acc;
    __syncthreads();
    if (threadIdx.x == 0) out[0] = sm[0] + sm[1] + sm[2] + sm[3];
}

extern "C" void kernel_launch(void* const* d_in, const int* in_sizes, int n_in,
                              void* d_out, int out_size, void* d_ws, size_t ws_size,
                              hipStream_t stream) {
    const float* preds  = (const float*)d_in[0];
    const float* labels = (const float*)d_in[1];
    const int*   cls    = (const int*)d_in[2];
    float* out = (float*)d_out;
    float* ws  = (float*)d_ws;

    const int B = in_sizes[2];                        // 16384 rows
    const int rows_per_block = 4 * RPW;               // 16
    const int blocks = (B + rows_per_block - 1) / rows_per_block;  // 1024

    vp_rows<<<blocks, 256, 0, stream>>>(preds, labels, cls, ws, B);
    vp_reduce<<<1, 256, 0, stream>>>(ws, out, blocks);
}